// Round 1
// baseline (2857.230 us; speedup 1.0000x reference)
//
#include <hip/hip_runtime.h>
#include <cmath>

// Problem constants
constexpr int Vn = 23262, En = 300, Hn = 1024, Sn = 2048, Bn = 64;
constexpr int NCHUNK = 16;               // S-chunks for attention partials
constexpr int SCHUNK = Sn / NCHUNK;      // 128 positions per block
constexpr size_t HN_OFF = (size_t)Bn * Vn;           // 1488768
constexpr size_t CN_OFF = HN_OFF + (size_t)Bn * Hn;  // 1554304

// ---------------------------------------------------------------------------
// K1: q[b][h] = sum_k h0[b][k] * W_in[k][h]   (coalesced over h)
// grid (H/256, B/4), block 256
__global__ __launch_bounds__(256) void k1_q(const float* __restrict__ h0,
                                            const float* __restrict__ Win,
                                            float* __restrict__ q) {
    int h  = blockIdx.x * 256 + threadIdx.x;
    int b0 = blockIdx.y * 4;
    float a0 = 0.f, a1 = 0.f, a2 = 0.f, a3 = 0.f;
    #pragma unroll 8
    for (int k = 0; k < Hn; ++k) {
        float wv = Win[(size_t)k * Hn + h];
        a0 += h0[(b0 + 0) * Hn + k] * wv;
        a1 += h0[(b0 + 1) * Hn + k] * wv;
        a2 += h0[(b0 + 2) * Hn + k] * wv;
        a3 += h0[(b0 + 3) * Hn + k] * wv;
    }
    q[(b0 + 0) * Hn + h] = a0;
    q[(b0 + 1) * Hn + h] = a1;
    q[(b0 + 2) * Hn + h] = a2;
    q[(b0 + 3) * Hn + h] = a3;
}

// ---------------------------------------------------------------------------
// K2: flash-style attention partials. grid (B, NCHUNK), block 256 (4 waves).
// Thread (w,l) owns h-slice [w*256 + l*4 .. +4). enc read once, kept in regs.
__global__ __launch_bounds__(256) void k2_attn(const float* __restrict__ enc,
                                               const float* __restrict__ q,
                                               float* __restrict__ part_ctx,
                                               float* __restrict__ part_ml) {
    int b = blockIdx.x, chunk = blockIdx.y;
    int t = threadIdx.x, w = t >> 6, l = t & 63;
    int h4 = w * 256 + l * 4;
    float4 q4 = *(const float4*)(q + (size_t)b * Hn + h4);
    float m = -INFINITY, lsum = 0.f;
    float4 ctx = {0.f, 0.f, 0.f, 0.f};
    __shared__ float red[4][8];
    int s0 = chunk * SCHUNK;
    for (int tile = 0; tile < SCHUNK / 8; ++tile) {
        const float* base = enc + (size_t)(s0 + tile * 8) * (Bn * Hn) + (size_t)b * Hn + h4;
        float4 e[8];
        #pragma unroll
        for (int j = 0; j < 8; ++j)
            e[j] = *(const float4*)(base + (size_t)j * (Bn * Hn));
        float pd[8];
        #pragma unroll
        for (int j = 0; j < 8; ++j) {
            float v = e[j].x * q4.x + e[j].y * q4.y + e[j].z * q4.z + e[j].w * q4.w;
            #pragma unroll
            for (int off = 32; off > 0; off >>= 1)
                v += __shfl_xor(v, off, 64);
            pd[j] = v;
        }
        __syncthreads();            // previous tile's reads of red[] done
        if (l == 0) {
            #pragma unroll
            for (int j = 0; j < 8; ++j) red[w][j] = pd[j];
        }
        __syncthreads();
        float sc[8];
        #pragma unroll
        for (int j = 0; j < 8; ++j)
            sc[j] = red[0][j] + red[1][j] + red[2][j] + red[3][j];
        float mt = sc[0];
        #pragma unroll
        for (int j = 1; j < 8; ++j) mt = fmaxf(mt, sc[j]);
        float mn = fmaxf(m, mt);
        float alpha = __expf(m - mn);           // m=-inf first tile -> 0
        float p[8], ps = 0.f;
        #pragma unroll
        for (int j = 0; j < 8; ++j) { p[j] = __expf(sc[j] - mn); ps += p[j]; }
        lsum = lsum * alpha + ps;
        ctx.x *= alpha; ctx.y *= alpha; ctx.z *= alpha; ctx.w *= alpha;
        #pragma unroll
        for (int j = 0; j < 8; ++j) {
            ctx.x += p[j] * e[j].x; ctx.y += p[j] * e[j].y;
            ctx.z += p[j] * e[j].z; ctx.w += p[j] * e[j].w;
        }
        m = mn;
    }
    *(float4*)(part_ctx + ((size_t)b * NCHUNK + chunk) * Hn + h4) = ctx;
    if (t == 0) {
        part_ml[((size_t)b * NCHUNK + chunk) * 2 + 0] = m;
        part_ml[((size_t)b * NCHUNK + chunk) * 2 + 1] = lsum;
    }
}

// ---------------------------------------------------------------------------
// K3: merge attention partials -> context; build xbuf = [context ; h0] [64][2048]
// grid (B), block 256
__global__ __launch_bounds__(256) void k3_reduce(const float* __restrict__ part_ctx,
                                                 const float* __restrict__ part_ml,
                                                 const float* __restrict__ h0,
                                                 float* __restrict__ xbuf) {
    int b = blockIdx.x, t = threadIdx.x;
    float mv[NCHUNK], lv[NCHUNK];
    float M = -INFINITY;
    #pragma unroll
    for (int c = 0; c < NCHUNK; ++c) {
        mv[c] = part_ml[((size_t)b * NCHUNK + c) * 2 + 0];
        lv[c] = part_ml[((size_t)b * NCHUNK + c) * 2 + 1];
        M = fmaxf(M, mv[c]);
    }
    float L = 0.f;
    #pragma unroll
    for (int c = 0; c < NCHUNK; ++c) { mv[c] = __expf(mv[c] - M); L += lv[c] * mv[c]; }
    float inv = 1.f / L;
    int h4 = t * 4;
    float4 acc = {0.f, 0.f, 0.f, 0.f};
    #pragma unroll
    for (int c = 0; c < NCHUNK; ++c) {
        float4 pc = *(const float4*)(part_ctx + ((size_t)b * NCHUNK + c) * Hn + h4);
        float s = mv[c];
        acc.x += s * pc.x; acc.y += s * pc.y; acc.z += s * pc.z; acc.w += s * pc.w;
    }
    acc.x *= inv; acc.y *= inv; acc.z *= inv; acc.w *= inv;
    *(float4*)(xbuf + (size_t)b * 2048 + h4) = acc;
    *(float4*)(xbuf + (size_t)b * 2048 + Hn + h4) = *(const float4*)(h0 + (size_t)b * Hn + h4);
}

// ---------------------------------------------------------------------------
// K_emb: lstm_in[b][1024 + e] = emb[tokens[b]][e], zero-pad cols [1324,1344)
// grid (80), block 256. lstm_in stride 1344.
__global__ __launch_bounds__(256) void k_emb(const int* __restrict__ tokens,
                                             const float* __restrict__ emb,
                                             float* __restrict__ lstm_in) {
    int idx = blockIdx.x * 256 + threadIdx.x;     // 64 * 320
    if (idx >= Bn * 320) return;
    int b = idx / 320, e = idx - b * 320;
    lstm_in[(size_t)b * 1344 + Hn + e] = (e < En) ? emb[(size_t)tokens[b] * En + e] : 0.f;
}

// ---------------------------------------------------------------------------
// Generic batched GEMV: out[b][n] = act( bias(n) + sum_j X1[b][j]W1[n][j]
//                                               (+ sum_j X2[b][j]W2[n][j]) )
// lane = b (B == 64 == wavefront!). Each wave handles NPW rows.
// X staged in LDS per 32-col chunk (coalesced); W rows are wave-uniform loads.
// LDS-transpose epilogue for coalesced stores.
template <int NPW, bool DO_TANH>
__global__ __launch_bounds__(256) void bgemv_k(
    const float* __restrict__ W1, const float* __restrict__ X1, int Ka, int x1st,
    const float* __restrict__ W2, const float* __restrict__ X2, int Kb, int x2st,
    const float* __restrict__ bias1, const float* __restrict__ bias2,
    float* __restrict__ out, int ostride, int N) {
    __shared__ float xs[64 * 36];
    __shared__ float st[4][NPW][65];
    int t = threadIdx.x, w = t >> 6, l = t & 63;
    int nb = blockIdx.x * (4 * NPW);
    int n0 = nb + w * NPW;
    float acc[NPW];
    #pragma unroll
    for (int i = 0; i < NPW; ++i) {
        int n = n0 + i;
        float bv = 0.f;
        if (n < N) {
            if (bias1) bv += bias1[n];
            if (bias2) bv += bias2[n];
        }
        acc[i] = bv;
    }
    for (int pass = 0; pass < 2; ++pass) {
        const float* W = pass ? W2 : W1;
        const float* X = pass ? X2 : X1;
        int K   = pass ? Kb : Ka;
        int xst = pass ? x2st : x1st;
        if (!W) continue;   // uniform
        for (int kc = 0; kc < K; kc += 32) {
            int csz = min(32, K - kc);
            __syncthreads();
            if (csz == 32) {
                int bb = t >> 2, jb = (t & 3) * 8;
                const float* src = X + (size_t)bb * xst + kc + jb;
                *(float4*)&xs[bb * 36 + jb]     = *(const float4*)src;
                *(float4*)&xs[bb * 36 + jb + 4] = *(const float4*)(src + 4);
            } else {
                for (int i = t; i < 64 * csz; i += 256) {
                    int bb = i / csz, j = i - bb * csz;
                    xs[bb * 36 + j] = X[(size_t)bb * xst + kc + j];
                }
            }
            __syncthreads();
            float4 xr[8];
            #pragma unroll
            for (int jj = 0; jj < 8; ++jj)
                xr[jj] = *(const float4*)&xs[l * 36 + jj * 4];
            if (csz == 32) {
                #pragma unroll
                for (int i = 0; i < NPW; ++i) {
                    int n = n0 + i;
                    if (n < N) {
                        const float* wr = W + (size_t)n * K + kc;
                        #pragma unroll
                        for (int jj = 0; jj < 8; ++jj) {
                            float4 w4 = *(const float4*)(wr + jj * 4);
                            acc[i] += w4.x * xr[jj].x + w4.y * xr[jj].y
                                    + w4.z * xr[jj].z + w4.w * xr[jj].w;
                        }
                    }
                }
            } else {
                int nj = csz >> 2;
                #pragma unroll
                for (int i = 0; i < NPW; ++i) {
                    int n = n0 + i;
                    if (n < N) {
                        const float* wr = W + (size_t)n * K + kc;
                        for (int jj = 0; jj < nj; ++jj) {
                            float4 w4 = *(const float4*)(wr + jj * 4);
                            acc[i] += w4.x * xr[jj].x + w4.y * xr[jj].y
                                    + w4.z * xr[jj].z + w4.w * xr[jj].w;
                        }
                    }
                }
            }
        }
    }
    __syncthreads();
    #pragma unroll
    for (int i = 0; i < NPW; ++i) {
        float v = acc[i];
        if (DO_TANH) v = tanhf(v);
        st[w][i][l] = v;
    }
    __syncthreads();
    for (int bb = 0; bb < 64; ++bb) {
        if (l < NPW) {
            int n = n0 + l;
            if (n < N) out[(size_t)bb * ostride + n] = st[w][l][bb];
        }
    }
}

// ---------------------------------------------------------------------------
// K5b: LSTM gate nonlinearity -> hN, cN into d_out. grid (256), block 256.
__global__ __launch_bounds__(256) void k5b(const float* __restrict__ gates,
                                           const float* __restrict__ c0,
                                           float* __restrict__ out) {
    int idx = blockIdx.x * 256 + threadIdx.x;   // 65536
    int b = idx >> 10, h = idx & 1023;
    float iv = gates[(size_t)b * 4096 + h];
    float fv = gates[(size_t)b * 4096 + 1024 + h];
    float gv = gates[(size_t)b * 4096 + 2048 + h];
    float ov = gates[(size_t)b * 4096 + 3072 + h];
    float si = 1.f / (1.f + __expf(-iv));
    float sf = 1.f / (1.f + __expf(-fv));
    float so = 1.f / (1.f + __expf(-ov));
    float c  = sf * c0[idx] + si * tanhf(gv);
    float hN = so * tanhf(c);
    out[HN_OFF + idx] = hN;
    out[CN_OFF + idx] = c;
}

// ---------------------------------------------------------------------------
extern "C" void kernel_launch(void* const* d_in, const int* in_sizes, int n_in,
                              void* d_out, int out_size, void* d_ws, size_t ws_size,
                              hipStream_t stream) {
    const int*   tokens = (const int*)d_in[0];
    const float* enc    = (const float*)d_in[1];
    const float* h0     = (const float*)d_in[2];
    const float* c0     = (const float*)d_in[3];
    const float* emb    = (const float*)d_in[4];
    const float* W_in   = (const float*)d_in[5];
    const float* W_out  = (const float*)d_in[6];
    const float* W_ih   = (const float*)d_in[7];
    const float* W_hh   = (const float*)d_in[8];
    const float* b_ih   = (const float*)d_in[9];
    const float* b_hh   = (const float*)d_in[10];
    const float* W_gen  = (const float*)d_in[11];
    const float* b_gen  = (const float*)d_in[12];
    float* out = (float*)d_out;
    float* ws  = (float*)d_ws;

    float* q        = ws;                              // 64*1024
    float* part_ctx = q + Bn * Hn;                     // 64*16*1024
    float* part_ml  = part_ctx + (size_t)Bn * NCHUNK * Hn;  // 64*16*2
    float* xbuf     = part_ml + Bn * NCHUNK * 2;       // 64*2048
    float* lstm_in  = xbuf + Bn * 2048;                // 64*1344
    float* gates    = lstm_in + Bn * 1344;             // 64*4096

    k_emb<<<80, 256, 0, stream>>>(tokens, emb, lstm_in);
    k1_q<<<dim3(Hn / 256, Bn / 4), 256, 0, stream>>>(h0, W_in, q);
    k2_attn<<<dim3(Bn, NCHUNK), 256, 0, stream>>>(enc, q, part_ctx, part_ml);
    k3_reduce<<<Bn, 256, 0, stream>>>(part_ctx, part_ml, h0, xbuf);
    // ctx_hat = tanh([context;h0] @ W_out^T) -> lstm_in[:, 0:1024]
    bgemv_k<4, true><<<Hn / 16, 256, 0, stream>>>(
        W_out, xbuf, 2 * Hn, 2 * Hn,
        nullptr, nullptr, 0, 0, nullptr, nullptr,
        lstm_in, 1344, Hn);
    // gates = lstm_in @ W_ih^T + b_ih + h0 @ W_hh^T + b_hh
    bgemv_k<4, false><<<4 * Hn / 16, 256, 0, stream>>>(
        W_ih, lstm_in, Hn + En, 1344,
        W_hh, h0, Hn, Hn, b_ih, b_hh,
        gates, 4 * Hn, 4 * Hn);
    k5b<<<256, 256, 0, stream>>>(gates, c0, out);
    // logits = hN @ W_gen^T + b_gen
    bgemv_k<8, false><<<(Vn + 31) / 32, 256, 0, stream>>>(
        W_gen, out + HN_OFF, Hn, Hn,
        nullptr, nullptr, 0, 0, b_gen, nullptr,
        out, Vn, Vn);
}

// Round 2
// 1615.014 us; speedup vs baseline: 1.7692x; 1.7692x over previous
//
#include <hip/hip_runtime.h>
#include <cmath>

constexpr int Vn = 23262, En = 300, Hn = 1024, Sn = 2048, Bn = 64;
constexpr int NCHUNK = 16;
constexpr int SCHUNK = Sn / NCHUNK;
constexpr size_t HN_OFF = (size_t)Bn * Vn;
constexpr size_t CN_OFF = HN_OFF + (size_t)Bn * Hn;

// ---------------------------------------------------------------------------
// gemv_part: part[(kb*64+b)*N + n] = sum_{k in [kb*KC, min(+KC,K))} W[n][k]*XT[k][b]
// lane = n (streams its own W row, 16B/lane/instr); XT rows are wave-uniform
// (scalar-load broadcast). acc[64] = one f32 per batch element.
__global__ __launch_bounds__(256) void gemv_part(
    const float* __restrict__ W, const float* __restrict__ XT,
    float* __restrict__ part, int N, int K, int KC, int n_tiles, int total_waves)
{
    int wave = blockIdx.x * 4 + (threadIdx.x >> 6);
    if (wave >= total_waves) return;
    int l = threadIdx.x & 63;
    int nb = wave % n_tiles, kb = wave / n_tiles;
    int n = nb * 64 + l;
    int k0 = kb * KC;
    int k1 = min(k0 + KC, K);
    const float* wrow = W + (size_t)(n < N ? n : N - 1) * K + k0;
    float acc[64];
#pragma unroll
    for (int b = 0; b < 64; ++b) acc[b] = 0.f;
    int len = k1 - k0;
    int kq = len & ~3;
    const float* xt = XT + (size_t)k0 * 64;
    for (int kc = 0; kc < kq; kc += 4) {
        float4 wv = *(const float4*)(wrow + kc);
        const float* x0 = xt + (size_t)kc * 64;
#pragma unroll
        for (int b = 0; b < 64; ++b) acc[b] += wv.x * x0[b];
#pragma unroll
        for (int b = 0; b < 64; ++b) acc[b] += wv.y * x0[64 + b];
#pragma unroll
        for (int b = 0; b < 64; ++b) acc[b] += wv.z * x0[128 + b];
#pragma unroll
        for (int b = 0; b < 64; ++b) acc[b] += wv.w * x0[192 + b];
    }
    for (int kc = kq; kc < len; ++kc) {
        float wv = wrow[kc];
        const float* x0 = xt + (size_t)kc * 64;
#pragma unroll
        for (int b = 0; b < 64; ++b) acc[b] += wv * x0[b];
    }
    if (n < N) {
        float* p = part + (size_t)(kb * 64) * N + n;
#pragma unroll
        for (int b = 0; b < 64; ++b) p[(size_t)b * N] = acc[b];   // coalesced over lanes
    }
}

// ---------------------------------------------------------------------------
// reduce_straight: out[b][n] = bias?[n] + sum_s part[s][b][n]. grid (ceil(N/256), B)
template <int S, bool BIAS>
__global__ __launch_bounds__(256) void reduce_straight(
    const float* __restrict__ part, const float* __restrict__ bias,
    float* __restrict__ out, int N)
{
    int b = blockIdx.y;
    int n = blockIdx.x * 256 + threadIdx.x;
    if (n >= N) return;
    float a = BIAS ? bias[n] : 0.f;
#pragma unroll
    for (int s = 0; s < S; ++s) a += part[((size_t)s * 64 + b) * N + n];
    out[(size_t)b * N + n] = a;
}

// ---------------------------------------------------------------------------
// trans_reduce: outT[n][b] = act(sum_s part[s][b][n]), N = 1024 fixed. grid 16.
template <int S, bool TANH>
__global__ __launch_bounds__(256) void trans_reduce(
    const float* __restrict__ part, float* __restrict__ outT)
{
    __shared__ float tile[64][65];
    int t = threadIdx.x, l = t & 63, r = t >> 6;
    int n0 = blockIdx.x * 64;
    for (int bg = 0; bg < 16; ++bg) {
        int b = bg * 4 + r;
        float a = 0.f;
#pragma unroll
        for (int s = 0; s < S; ++s) a += part[((size_t)s * 64 + b) * 1024 + n0 + l];
        if (TANH) a = tanhf(a);
        tile[l][b] = a;
    }
    __syncthreads();
    for (int hg = 0; hg < 16; ++hg)
        outT[(size_t)(n0 + hg * 4 + r) * 64 + l] = tile[hg * 4 + r][l];
}

// ---------------------------------------------------------------------------
// t_win: WinT[h][k] = W_in[k][h], 1024x1024, grid (16,16)
__global__ __launch_bounds__(256) void t_win(const float* __restrict__ Wi,
                                             float* __restrict__ WiT)
{
    __shared__ float tile[64][65];
    int t = threadIdx.x, l = t & 63, r = t >> 6;
    int h0b = blockIdx.x * 64, k0b = blockIdx.y * 64;
    for (int ig = 0; ig < 16; ++ig)
        tile[ig * 4 + r][l] = Wi[(size_t)(k0b + ig * 4 + r) * 1024 + h0b + l];
    __syncthreads();
    for (int ig = 0; ig < 16; ++ig)
        WiT[(size_t)(h0b + ig * 4 + r) * 1024 + k0b + l] = tile[l][ig * 4 + r];
}

// ---------------------------------------------------------------------------
// k_emb: embT[e][b] = emb[tokens[b]][e]. grid 75.
__global__ __launch_bounds__(256) void k_emb(const int* __restrict__ tokens,
                                             const float* __restrict__ emb,
                                             float* __restrict__ embT)
{
    int idx = blockIdx.x * 256 + threadIdx.x;   // 300*64 = 19200
    if (idx >= En * Bn) return;
    int b = idx & 63, e = idx >> 6;
    embT[(size_t)e * 64 + b] = emb[(size_t)tokens[b] * En + e];
}

// ---------------------------------------------------------------------------
// k2_attn: flash-style attention partials. grid (B, NCHUNK), block 256.
__global__ __launch_bounds__(256) void k2_attn(const float* __restrict__ enc,
                                               const float* __restrict__ q,
                                               float* __restrict__ part_ctx,
                                               float* __restrict__ part_ml) {
    int b = blockIdx.x, chunk = blockIdx.y;
    int t = threadIdx.x, w = t >> 6, l = t & 63;
    int h4 = w * 256 + l * 4;
    float4 q4 = *(const float4*)(q + (size_t)b * Hn + h4);
    float m = -INFINITY, lsum = 0.f;
    float4 ctx = {0.f, 0.f, 0.f, 0.f};
    __shared__ float red[4][8];
    int s0 = chunk * SCHUNK;
    for (int tile = 0; tile < SCHUNK / 8; ++tile) {
        const float* base = enc + (size_t)(s0 + tile * 8) * (Bn * Hn) + (size_t)b * Hn + h4;
        float4 e[8];
#pragma unroll
        for (int j = 0; j < 8; ++j)
            e[j] = *(const float4*)(base + (size_t)j * (Bn * Hn));
        float pd[8];
#pragma unroll
        for (int j = 0; j < 8; ++j) {
            float v = e[j].x * q4.x + e[j].y * q4.y + e[j].z * q4.z + e[j].w * q4.w;
#pragma unroll
            for (int off = 32; off > 0; off >>= 1)
                v += __shfl_xor(v, off, 64);
            pd[j] = v;
        }
        __syncthreads();
        if (l == 0) {
#pragma unroll
            for (int j = 0; j < 8; ++j) red[w][j] = pd[j];
        }
        __syncthreads();
        float sc[8];
#pragma unroll
        for (int j = 0; j < 8; ++j)
            sc[j] = red[0][j] + red[1][j] + red[2][j] + red[3][j];
        float mt = sc[0];
#pragma unroll
        for (int j = 1; j < 8; ++j) mt = fmaxf(mt, sc[j]);
        float mn = fmaxf(m, mt);
        float alpha = __expf(m - mn);
        float p[8], ps = 0.f;
#pragma unroll
        for (int j = 0; j < 8; ++j) { p[j] = __expf(sc[j] - mn); ps += p[j]; }
        lsum = lsum * alpha + ps;
        ctx.x *= alpha; ctx.y *= alpha; ctx.z *= alpha; ctx.w *= alpha;
#pragma unroll
        for (int j = 0; j < 8; ++j) {
            ctx.x += p[j] * e[j].x; ctx.y += p[j] * e[j].y;
            ctx.z += p[j] * e[j].z; ctx.w += p[j] * e[j].w;
        }
        m = mn;
    }
    *(float4*)(part_ctx + ((size_t)b * NCHUNK + chunk) * Hn + h4) = ctx;
    if (t == 0) {
        part_ml[((size_t)b * NCHUNK + chunk) * 2 + 0] = m;
        part_ml[((size_t)b * NCHUNK + chunk) * 2 + 1] = lsum;
    }
}

// ---------------------------------------------------------------------------
// k3_t: merge attention partials -> ctxT[h][b]. grid 16 (h-chunks of 64).
__global__ __launch_bounds__(256) void k3_t(const float* __restrict__ part_ctx,
                                            const float* __restrict__ part_ml,
                                            float* __restrict__ ctxT)
{
    __shared__ float wsc[NCHUNK * 64];
    __shared__ float tile[64][65];
    int t = threadIdx.x, l = t & 63, r = t >> 6;
    int h0b = blockIdx.x * 64;
    if (t < 64) {
        int b = t;
        float mv[NCHUNK], lv[NCHUNK], M = -INFINITY;
#pragma unroll
        for (int c = 0; c < NCHUNK; ++c) {
            mv[c] = part_ml[((size_t)b * NCHUNK + c) * 2 + 0];
            lv[c] = part_ml[((size_t)b * NCHUNK + c) * 2 + 1];
            M = fmaxf(M, mv[c]);
        }
        float L = 0.f;
#pragma unroll
        for (int c = 0; c < NCHUNK; ++c) { mv[c] = __expf(mv[c] - M); L += lv[c] * mv[c]; }
        float inv = 1.f / L;
#pragma unroll
        for (int c = 0; c < NCHUNK; ++c) wsc[c * 64 + b] = mv[c] * inv;
    }
    __syncthreads();
    for (int bg = 0; bg < 16; ++bg) {
        int b = bg * 4 + r;
        float a = 0.f;
#pragma unroll
        for (int c = 0; c < NCHUNK; ++c)
            a += wsc[c * 64 + b] * part_ctx[((size_t)b * NCHUNK + c) * 1024 + h0b + l];
        tile[l][b] = a;
    }
    __syncthreads();
    for (int hg = 0; hg < 16; ++hg)
        ctxT[(size_t)(h0b + hg * 4 + r) * 64 + l] = tile[hg * 4 + r][l];
}

// ---------------------------------------------------------------------------
// r3_gates: gates reduce + biases + LSTM nonlinearity -> hN,cN (d_out) + hNT.
// grid 16 (h-chunks of 64).
__global__ __launch_bounds__(256) void r3_gates(const float* __restrict__ part_g,
                                                const float* __restrict__ b_ih,
                                                const float* __restrict__ b_hh,
                                                const float* __restrict__ c0,
                                                float* __restrict__ out,
                                                float* __restrict__ hNT)
{
    __shared__ float tile[64][65];
    int t = threadIdx.x, l = t & 63, r = t >> 6;
    int h0b = blockIdx.x * 64;
    int h = h0b + l;
    for (int bg = 0; bg < 16; ++bg) {
        int b = bg * 4 + r;
        float gi = b_ih[h] + b_hh[h];
        float gf = b_ih[h + 1024] + b_hh[h + 1024];
        float gg = b_ih[h + 2048] + b_hh[h + 2048];
        float go = b_ih[h + 3072] + b_hh[h + 3072];
#pragma unroll
        for (int s = 0; s < 16; ++s) {
            const float* base = part_g + ((size_t)s * 64 + b) * 4096;
            gi += base[h];
            gf += base[h + 1024];
            gg += base[h + 2048];
            go += base[h + 3072];
        }
        float c0v = c0[(size_t)b * 1024 + h];
        float si = 1.f / (1.f + __expf(-gi));
        float sf = 1.f / (1.f + __expf(-gf));
        float so = 1.f / (1.f + __expf(-go));
        float c  = sf * c0v + si * tanhf(gg);
        float hN = so * tanhf(c);
        out[HN_OFF + (size_t)b * 1024 + h] = hN;
        out[CN_OFF + (size_t)b * 1024 + h] = c;
        tile[l][b] = hN;
    }
    __syncthreads();
    for (int hg = 0; hg < 16; ++hg)
        hNT[(size_t)(h0b + hg * 4 + r) * 64 + l] = tile[hg * 4 + r][l];
}

// ---------------------------------------------------------------------------
extern "C" void kernel_launch(void* const* d_in, const int* in_sizes, int n_in,
                              void* d_out, int out_size, void* d_ws, size_t ws_size,
                              hipStream_t stream) {
    const int*   tokens = (const int*)d_in[0];
    const float* enc    = (const float*)d_in[1];
    const float* h0     = (const float*)d_in[2];
    const float* c0     = (const float*)d_in[3];
    const float* emb    = (const float*)d_in[4];
    const float* W_in   = (const float*)d_in[5];
    const float* W_out  = (const float*)d_in[6];
    const float* W_ih   = (const float*)d_in[7];
    const float* W_hh   = (const float*)d_in[8];
    const float* b_ih   = (const float*)d_in[9];
    const float* b_hh   = (const float*)d_in[10];
    const float* W_gen  = (const float*)d_in[11];
    const float* b_gen  = (const float*)d_in[12];
    float* out = (float*)d_out;
    float* X   = (float*)d_ws;                     // 4,466,304-float arena (time-multiplexed)

    // arena X (overlaid by lifetime):
    float* WinT     = X + 0;          // 1,048,576   [t_win  -> G1]
    float* part_q   = X + 1048576;    // 1,048,576   [G1 -> R1]
    float* part_ctx = X + 2097152;    // 1,048,576   [k2 -> k3]
    float* part_ml  = X + 3145728;    //     2,048   [k2 -> k3]
    float* part_co  = X + 1048576;    // 2,097,152   [G2 -> R2]  (over dead part_q/part_ctx/ml)
    float* part_g   = X + 0;          // 4,194,304   [G3 -> R3]  (over everything dead)
    float* part_v   = X + 0;          // 4,466,304   [G4 -> R4]
    // persistent small region Y:
    float* Y        = X + 4466304;
    float* ctxT     = Y + 0;          // 65,536  (P: [ctxT ; h0T] = Wout's XT, K=2048)
    float* h0T      = Y + 65536;      // 65,536
    float* chT      = Y + 131072;     // 65,536  (Q: [ctx_hatT ; embT] = W_ih's XT, K=1324)
    float* embT     = Y + 196608;     // 19,200
    float* q        = Y + 215808;     // 65,536
    float* hNT      = Y + 281344;     // 65,536
    // total ws need: 4,813,184 floats = 19.3 MB

    t_win<<<dim3(16, 16), 256, 0, stream>>>(W_in, WinT);
    trans_reduce<1, false><<<16, 256, 0, stream>>>(h0, h0T);
    k_emb<<<75, 256, 0, stream>>>(tokens, emb, embT);
    // q = h0 @ W_in  (rows of WinT, XT = h0T), KB=16, KC=64
    gemv_part<<<64, 256, 0, stream>>>(WinT, h0T, part_q, 1024, 1024, 64, 16, 256);
    reduce_straight<16, false><<<dim3(4, 64), 256, 0, stream>>>(part_q, nullptr, q, 1024);
    k2_attn<<<dim3(Bn, NCHUNK), 256, 0, stream>>>(enc, q, part_ctx, part_ml);
    k3_t<<<16, 256, 0, stream>>>(part_ctx, part_ml, ctxT);
    // ctx_hat = tanh([ctx;h0] @ W_out^T): XT = [ctxT;h0T] contiguous, KB=32, KC=64
    gemv_part<<<128, 256, 0, stream>>>(W_out, ctxT, part_co, 1024, 2048, 64, 16, 512);
    trans_reduce<32, true><<<16, 256, 0, stream>>>(part_co, chT);
    // gates: W_ih @ [ctx_hat;emb] (KB=8, KC=168) + W_hh @ h0 (KB=8, KC=128)
    gemv_part<<<128, 256, 0, stream>>>(W_ih, chT, part_g, 4096, 1324, 168, 64, 512);
    gemv_part<<<128, 256, 0, stream>>>(W_hh, h0T, part_g + (size_t)8 * 64 * 4096,
                                       4096, 1024, 128, 64, 512);
    r3_gates<<<16, 256, 0, stream>>>(part_g, b_ih, b_hh, c0, out, hNT);
    // logits = hN @ W_gen^T + b_gen: KB=3, KC=344
    gemv_part<<<273, 256, 0, stream>>>(W_gen, hNT, part_v, Vn, 1024, 344, 364, 1092);
    reduce_straight<3, true><<<dim3(91, 64), 256, 0, stream>>>(part_v, b_gen, out, Vn);
}